// Round 4
// baseline (114.150 us; speedup 1.0000x reference)
//
#include <hip/hip_runtime.h>
#include <hip/hip_bf16.h>

// B=8, T=2048, C=1024, H=64.  ref: wei=(k q^T)/32 causal, softmax over s, @v.
// R4: DS-pipe-free attention. QK^T computed SWAPPED (A=Q rows=s, B=K cols=t)
// with 32x32x16 MFMA so t = lane&31 -> softmax is lane-scalar (no butterflies,
// no LDS P-transpose). O accumulated TRANSPOSED (O^T = V^T * P^T) so rescale
// is lane-scalar too. P redistribution = 8 cvt_pk + 8 lane^32 shuffles.
// Split-s (CHUNK = 4 s-tiles of 32 = 128 s) for occupancy; 4 waves/block share
// the same s-chunk (Q/V loads L1-hit). Partials bf16-packed; combine merges.

typedef __attribute__((ext_vector_type(8))) short short8;   // 8 bf16
typedef __attribute__((ext_vector_type(4))) float f32x4;
typedef __attribute__((ext_vector_type(16))) float f32x16;
typedef __attribute__((ext_vector_type(4))) unsigned int u32x4;
typedef unsigned int u32;

#define BATCH 8
#define T 2048
#define CDIM 1024
#define HD 64
#define SLOTS 544                 // split slots per batch
#define QK_SCALE 0.04508422f      // log2(e)/32  (exp2-domain softmax)

static __device__ __forceinline__ short f2bf(float f) {
    return __builtin_bit_cast(short, __float2bfloat16(f));   // RNE
}
static __device__ __forceinline__ float bf2f(unsigned short s) {
    u32 u = ((u32)s) << 16;
    return __builtin_bit_cast(float, u);
}
static __device__ __forceinline__ u32 packbf(float lo, float hi) {
    return (u32)(unsigned short)f2bf(lo) | ((u32)(unsigned short)f2bf(hi) << 16);
}
static __device__ __forceinline__ f32x4 mfma16(short8 a, short8 b, f32x4 c) {
    return __builtin_amdgcn_mfma_f32_16x16x32_bf16(a, b, c, 0, 0, 0);
}
static __device__ __forceinline__ f32x16 mfma32(short8 a, short8 b, f32x16 c) {
    return __builtin_amdgcn_mfma_f32_32x32x16_bf16(a, b, c, 0, 0, 0);
}

// ---------------- W -> bf16 (Wk pre-scaled) ----------------
__global__ __launch_bounds__(256) void wcvt_kernel(
    const float* __restrict__ Wk, const float* __restrict__ Wq,
    const float* __restrict__ Wv, short* __restrict__ wbf)
{
    const int gt = blockIdx.x * 256 + threadIdx.x;
    const int base = gt * 8;
    const int p = base >> 16;
    const int off = base & 65535;
    const float* __restrict__ src = (p == 0) ? Wk : (p == 1 ? Wq : Wv);
    const float sc = (p == 0) ? QK_SCALE : 1.0f;
    f32x4 a = *(const f32x4*)(src + off);
    f32x4 b = *(const f32x4*)(src + off + 4);
    short8 o;
#pragma unroll
    for (int e = 0; e < 4; ++e) { o[e] = f2bf(a[e] * sc); o[e + 4] = f2bf(b[e] * sc); }
    *(short8*)(wbf + p * 65536 + off) = o;
}

// ---------------- projection: LDS-free main loop, x read once ----------------
// block = 64 rows x one proj; same-m p-triplets placed 8 blocks apart so they
// share an XCD L2 (x fetched once); 4 waves of a block read identical W
// addresses (L1 hits).
__global__ __launch_bounds__(256) void proj_kernel(
    const float* __restrict__ x, const short* __restrict__ wbf,
    short* __restrict__ kp, short* __restrict__ qp, short* __restrict__ vt)
{
    __shared__ __align__(16) short stg[4][1024];
    const int tid = threadIdx.x, wid = tid >> 6, lane = tid & 63;
    const int c = lane & 15, g = lane >> 4;
    const int bid = blockIdx.x;
    const int mg = (bid / 24) * 8 + (bid & 7);     // 0..255 (64-row group)
    const int p  = (bid >> 3) % 3;
    const int m0 = mg * 64 + wid * 16;
    const short* __restrict__ Wp = wbf + p * 65536;
    const float* __restrict__ xr = x + (size_t)(m0 + c) * CDIM;

    f32x4 acc[4] = {};
    for (int ks = 0; ks < 32; ++ks) {
        const float* ax = xr + ks * 32 + g * 8;
        f32x4 a0 = *(const f32x4*)ax;
        f32x4 a1 = *(const f32x4*)(ax + 4);
        short8 af = { f2bf(a0[0]), f2bf(a0[1]), f2bf(a0[2]), f2bf(a0[3]),
                      f2bf(a1[0]), f2bf(a1[1]), f2bf(a1[2]), f2bf(a1[3]) };
#pragma unroll
        for (int ct = 0; ct < 4; ++ct) {
            short8 bf = *(const short8*)&Wp[(size_t)(ct * 16 + c) * CDIM + ks * 32 + g * 8];
            acc[ct] = mfma16(af, bf, acc[ct]);
        }
    }
    short* st_ = stg[wid];
    if (p < 2) {
        // stage [16 t][64 d], then coalesced row stores
#pragma unroll
        for (int ct = 0; ct < 4; ++ct)
#pragma unroll
            for (int r = 0; r < 4; ++r)
                st_[(g * 4 + r) * 64 + ct * 16 + c] = f2bf(acc[ct][r]);
        short* __restrict__ dst = (p == 0) ? kp : qp;
        const int rr = lane >> 2, qq = lane & 3;
        short8 v0 = *(short8*)&st_[rr * 64 + qq * 16];
        short8 v1 = *(short8*)&st_[rr * 64 + qq * 16 + 8];
        *(short8*)&dst[(size_t)(m0 + rr) * HD + qq * 16] = v0;
        *(short8*)&dst[(size_t)(m0 + rr) * HD + qq * 16 + 8] = v1;
    } else {
        // stage transposed [64 d][16 t] (u32-packed pairs), store vt rows
#pragma unroll
        for (int ct = 0; ct < 4; ++ct) {
            u32 w0 = packbf(acc[ct][0], acc[ct][1]);
            u32 w1 = packbf(acc[ct][2], acc[ct][3]);
            *(u32*)&st_[(ct * 16 + c) * 16 + g * 4]     = w0;
            *(u32*)&st_[(ct * 16 + c) * 16 + g * 4 + 2] = w1;
        }
        const int bb = m0 >> 11, sl = m0 & 2047;
        short8 v0 = *(short8*)&st_[lane * 16];
        short8 v1 = *(short8*)&st_[lane * 16 + 8];
        short* dv = vt + (size_t)(bb * 64 + lane) * T + sl;
        *(short8*)&dv[0] = v0;
        *(short8*)&dv[8] = v1;
    }
}

// ---------------- attention (split-s, DS-free inner loop) ----------------
// grid (136, 8): block x -> (ck, bo); wave wid -> t-tile i = 4*(ck+bo)+wid.
// Wave processes s-tiles [4ck, min(4ck+4, i+1)), 32 s each.
__global__ __launch_bounds__(256) void attn_kernel(
    const short* __restrict__ kp, const short* __restrict__ qp,
    const short* __restrict__ vt,
    u32* __restrict__ pO, float* __restrict__ pML)
{
    const int tid = threadIdx.x, wid = tid >> 6, lane = tid & 63;
    const int l5 = lane & 31, h = lane >> 5;
    const int b = blockIdx.y;

    int e = blockIdx.x, ck = 0;
    while (e >= 16 - ck) { e -= 16 - ck; ++ck; }
    const int bo = e;
    const int i = 4 * (ck + bo) + wid;       // t-tile (32 rows)
    const int t0 = i * 32;
    const int st0 = 4 * ck;
    const int stEnd = min(st0 + 4, i + 1);

    const short* __restrict__ kpb = kp + (size_t)b * T * HD;
    const short* __restrict__ qpb = qp + (size_t)b * T * HD;
    const short* __restrict__ vtb = vt + (size_t)b * HD * T;

    // K B-frags hoisted: lane holds K[t0+l5][16ks + 8h + j]
    short8 kf[4];
#pragma unroll
    for (int ks = 0; ks < 4; ++ks)
        kf[ks] = *(const short8*)&kpb[(size_t)(t0 + l5) * HD + ks * 16 + h * 8];

    float m = -1e30f, l = 0.f;
    f32x16 o0 = {}, o1 = {};                 // O^T: rows=d (regs), col=t (lane)

    for (int st = st0; st < stEnd; ++st) {
        const int s0 = st * 32;
        // ---- scores C[s][t]: col = t = l5, rows s over regs ----
        f32x16 Cs = {};
#pragma unroll
        for (int ks = 0; ks < 4; ++ks) {
            short8 qf = *(const short8*)&qpb[(size_t)(s0 + l5) * HD + ks * 16 + h * 8];
            Cs = mfma32(qf, kf[ks], Cs);
        }
        if (st == i) {                       // diagonal tile: mask s > t
#pragma unroll
            for (int r = 0; r < 16; ++r) {
                const int srow = (r & 3) + 8 * (r >> 2) + 4 * h;
                if (srow > l5) Cs[r] = -1e30f;
            }
        }
        // ---- lane-scalar online softmax (t = l5) ----
        float mx = Cs[0];
#pragma unroll
        for (int r = 1; r < 16; ++r) mx = fmaxf(mx, Cs[r]);
        mx = fmaxf(mx, __shfl_xor(mx, 32));
        const float mnew = fmaxf(m, mx);
        const float alpha = exp2f(m - mnew);
        m = mnew;
        float pv[16]; float rs = 0.f;
#pragma unroll
        for (int r = 0; r < 16; ++r) { pv[r] = exp2f(Cs[r] - m); rs += pv[r]; }
        rs += __shfl_xor(rs, 32);
        l = l * alpha + rs;
#pragma unroll
        for (int r = 0; r < 16; ++r) { o0[r] *= alpha; o1[r] *= alpha; }

        // ---- pack P (t-local) and build P^T B-frags via lane^32 exchange ----
        u32 pk[8], fk[8];
#pragma unroll
        for (int q = 0; q < 8; ++q) pk[q] = packbf(pv[2 * q], pv[2 * q + 1]);
#pragma unroll
        for (int q = 0; q < 8; ++q) fk[q] = __shfl_xor(pk[q], 32);
        // B-frag(ks): lane supplies P[t=l5][s = 16ks + 8h + 0..7]
        u32x4 b0 = { h ? fk[2] : pk[0], h ? fk[3] : pk[1],
                     h ? pk[2] : fk[0], h ? pk[3] : fk[1] };
        u32x4 b1 = { h ? fk[6] : pk[4], h ? fk[7] : pk[5],
                     h ? pk[6] : fk[4], h ? pk[7] : fk[5] };
        short8 pf0 = __builtin_bit_cast(short8, b0);
        short8 pf1 = __builtin_bit_cast(short8, b1);

        // ---- O^T += V^T * P^T : A-frag = V[s][d] read as vt[d][s] rows ----
        short8 vf00 = *(const short8*)&vtb[(size_t)l5 * T + s0 + h * 8];
        short8 vf01 = *(const short8*)&vtb[(size_t)l5 * T + s0 + 16 + h * 8];
        short8 vf10 = *(const short8*)&vtb[(size_t)(32 + l5) * T + s0 + h * 8];
        short8 vf11 = *(const short8*)&vtb[(size_t)(32 + l5) * T + s0 + 16 + h * 8];
        o0 = mfma32(vf00, pf0, o0);
        o0 = mfma32(vf01, pf1, o0);
        o1 = mfma32(vf10, pf0, o1);
        o1 = mfma32(vf11, pf1, o1);
    }

    // ---- partial store: pO[slot][dpair=32][t=32] u32 (bf16 pairs) ----
    const int grp = i >> 2;
    const int slot = b * SLOTS + 2 * grp * (grp + 1) + (i & 3) * (grp + 1) + ck;
    u32* po = pO + (size_t)slot * 1024;
#pragma unroll
    for (int q = 0; q < 8; ++q) {
        const int dp = (q & 1) + 4 * (q >> 1) + 2 * h;
        po[dp * 32 + l5]        = packbf(o0[2 * q], o0[2 * q + 1]);
        po[(16 + dp) * 32 + l5] = packbf(o1[2 * q], o1[2 * q + 1]);
    }
    if (h == 0) {
        pML[(size_t)slot * 64 + l5]      = m;
        pML[(size_t)slot * 64 + 32 + l5] = l;
    }
}

// ---------------- combine partials ----------------
__global__ __launch_bounds__(256) void combine_kernel(
    const u32* __restrict__ pO, const float* __restrict__ pML,
    float* __restrict__ out)
{
    const int i = blockIdx.x, b = blockIdx.y;
    const int grp = i >> 2, nc = grp + 1;
    const int base = b * SLOTS + 2 * grp * (grp + 1) + (i & 3) * nc;
    const int tid = threadIdx.x;
    const int t = tid >> 3, ds8 = tid & 7;       // d = ds8*8 + 0..7

    float M = -1e30f;
    for (int c = 0; c < nc; ++c)
        M = fmaxf(M, pML[(size_t)(base + c) * 64 + t]);
    float L = 0.f;
    float acc[8] = {};
    for (int c = 0; c < nc; ++c) {
        const float mm = pML[(size_t)(base + c) * 64 + t];
        const float w = exp2f(mm - M);
        L += w * pML[(size_t)(base + c) * 64 + 32 + t];
        const u32* po = pO + (size_t)(base + c) * 1024;
#pragma unroll
        for (int u = 0; u < 4; ++u) {
            const u32 v = po[(ds8 * 4 + u) * 32 + t];
            acc[2 * u]     += w * bf2f((unsigned short)(v & 0xffff));
            acc[2 * u + 1] += w * bf2f((unsigned short)(v >> 16));
        }
    }
    const float inv = 1.f / L;
    f32x4 r0 = { acc[0] * inv, acc[1] * inv, acc[2] * inv, acc[3] * inv };
    f32x4 r1 = { acc[4] * inv, acc[5] * inv, acc[6] * inv, acc[7] * inv };
    float* op = out + ((size_t)b * T + i * 32 + t) * HD + ds8 * 8;
    *(f32x4*)op = r0;
    *(f32x4*)(op + 4) = r1;
}

extern "C" void kernel_launch(void* const* d_in, const int* in_sizes, int n_in,
                              void* d_out, int out_size, void* d_ws, size_t ws_size,
                              hipStream_t stream) {
    const float* x  = (const float*)d_in[0];
    const float* Wk = (const float*)d_in[1];
    const float* Wq = (const float*)d_in[2];
    const float* Wv = (const float*)d_in[3];
    float* out = (float*)d_out;

    short* kp  = (short*)d_ws;                          // [16384][64] bf16
    short* qp  = kp + (size_t)BATCH * T * HD;           // [16384][64] bf16
    short* vt  = qp + (size_t)BATCH * T * HD;           // [8][64][2048] bf16
    short* wbf = vt + (size_t)BATCH * T * HD;           // [3][64][1024] bf16
    u32*   pO  = (u32*)(wbf + 3 * 65536);               // [4352][1024] u32 (bf16 pairs)
    float* pML = (float*)(pO + (size_t)BATCH * SLOTS * 1024);  // [4352][64] f32

    wcvt_kernel<<<96, 256, 0, stream>>>(Wk, Wq, Wv, wbf);
    proj_kernel<<<768, 256, 0, stream>>>(x, wbf, kp, qp, vt);
    attn_kernel<<<dim3(136, BATCH), 256, 0, stream>>>(kp, qp, vt, pO, pML);
    combine_kernel<<<dim3(64, BATCH), 256, 0, stream>>>(pO, pML, out);
}

// Round 5
// 97.115 us; speedup vs baseline: 1.1754x; 1.1754x over previous
//
#include <hip/hip_runtime.h>
#include <hip/hip_bf16.h>

// B=8, T=2048, C=1024, H=64.  ref: wei=(k q^T)/32 causal, softmax over s, @v.
// R5: all hot loads 1-transaction coalesced via FRAG-MAJOR layouts.
//  - wcvt: W -> wfrag[p][d16][kk][lane]x8 (mfma16 B-frag order, Wk pre-scaled)
//  - proj: x read once, staged bf16 in LDS (dbuf, 528B pitch); MFMA from LDS
//          A-frags + coalesced wfrag B-frags; epilogue emits kfrag/qfrag/vfrag
//          (mfma32 frag order: element for lane l at base + l*16B).
//  - attn: ZERO LDS. Swapped QK (t=lane&31 -> lane-scalar softmax), O^T accum,
//          P redistribution via 4x v_permlane32_swap_b32 (VALU, no DS).
//  - combine: merge split-s partials.

typedef __attribute__((ext_vector_type(8))) short short8;   // 8 bf16
typedef __attribute__((ext_vector_type(4))) float f32x4;
typedef __attribute__((ext_vector_type(16))) float f32x16;
typedef unsigned int u32;

#define BATCH 8
#define T 2048
#define CDIM 1024
#define HD 64
#define SLOTS 544                 // split slots per batch
#define QK_SCALE 0.04508422f      // log2(e)/32  (exp2-domain softmax)

static __device__ __forceinline__ short f2bf(float f) {
    return __builtin_bit_cast(short, __float2bfloat16(f));   // RNE
}
static __device__ __forceinline__ float bf2f(unsigned short s) {
    u32 u = ((u32)s) << 16;
    return __builtin_bit_cast(float, u);
}
static __device__ __forceinline__ u32 packbf(float lo, float hi) {
    return (u32)(unsigned short)f2bf(lo) | ((u32)(unsigned short)f2bf(hi) << 16);
}
static __device__ __forceinline__ f32x4 mfma16(short8 a, short8 b, f32x4 c) {
    return __builtin_amdgcn_mfma_f32_16x16x32_bf16(a, b, c, 0, 0, 0);
}
static __device__ __forceinline__ f32x16 mfma32(short8 a, short8 b, f32x16 c) {
    return __builtin_amdgcn_mfma_f32_32x32x16_bf16(a, b, c, 0, 0, 0);
}

// ---------------- W -> frag-major bf16 ----------------
// wfrag element index == global thread id * 8 (B-frag of 16x16x32:
// col = lane&15, k = kk*32 + (lane>>4)*8 + j).
__global__ __launch_bounds__(256) void wcvt_kernel(
    const float* __restrict__ Wk, const float* __restrict__ Wq,
    const float* __restrict__ Wv, short* __restrict__ wfrag)
{
    const int t = blockIdx.x * 256 + threadIdx.x;   // 0..24575
    const int lane = t & 63, kk = (t >> 6) & 31, d16 = (t >> 11) & 3, p = t >> 13;
    const float* __restrict__ W = (p == 0) ? Wk : (p == 1 ? Wq : Wv);
    const float sc = (p == 0) ? QK_SCALE : 1.0f;
    const float* src = W + (size_t)(d16 * 16 + (lane & 15)) * CDIM
                         + kk * 32 + ((lane >> 4) & 3) * 8;
    f32x4 a = *(const f32x4*)src;
    f32x4 b = *(const f32x4*)(src + 4);
    short8 o;
#pragma unroll
    for (int e = 0; e < 4; ++e) { o[e] = f2bf(a[e] * sc); o[e + 4] = f2bf(b[e] * sc); }
    *(short8*)(wfrag + (size_t)t * 8) = o;
}

// ---------------- projection ----------------
// 512 blocks x 256 thr. Block = 32 rows (one attn tile) x all 3 projs x K=1024.
// x staged bf16 in LDS (dbuf), k-chunks of 256.
#define XP 264   // x-tile pitch in shorts (528B): b128 frag reads spread evenly

#define LOADX(KC) \
    _Pragma("unroll") for (int u = 0; u < 8; ++u) \
        xr[u] = *(const f32x4*)(xbase + (KC) * 256 + u * 4);

#define WRITEX(BUF) \
    _Pragma("unroll") for (int u2 = 0; u2 < 4; ++u2) { \
        short8 v; \
        _Pragma("unroll") for (int e = 0; e < 4; ++e) { \
            v[e] = f2bf(xr[2 * u2][e]); v[e + 4] = f2bf(xr[2 * u2 + 1][e]); } \
        *(short8*)&xs[BUF][xrow * XP + kseg * 32 + u2 * 8] = v; }

#define COMPUTE(KC, BUF) \
    _Pragma("unroll") for (int kk = 0; kk < 8; ++kk) { \
        short8 af = *(short8*)&xs[BUF][(m16 * 16 + c) * XP + kk * 32 + g * 8]; \
        _Pragma("unroll") for (int j = 0; j < 6; ++j) { \
            const int q = half * 6 + j, p = q >> 2, d16 = q & 3; \
            short8 bf = *(const short8*)&wfrag[ \
                ((size_t)((p * 4 + d16) * 32 + (KC) * 8 + kk)) * 512 + lane * 8]; \
            acc[j] = mfma16(af, bf, acc[j]); } }

__global__ __launch_bounds__(256, 2) void proj_kernel(
    const float* __restrict__ x, const short* __restrict__ wfrag,
    short* __restrict__ kfrag, short* __restrict__ qfrag, short* __restrict__ vfrag)
{
    __shared__ __align__(16) short xs[2][32 * XP];

    const int tid = threadIdx.x, wid = tid >> 6, lane = tid & 63;
    const int c = lane & 15, g = lane >> 4;
    const int row0 = blockIdx.x * 32;
    const int m16 = wid & 1, half = wid >> 1;
    const int xrow = tid >> 3, kseg = tid & 7;
    const float* __restrict__ xbase = x + (size_t)(row0 + xrow) * CDIM + kseg * 32;

    f32x4 xr[8];
    f32x4 acc[6] = {};

    LOADX(0)
    WRITEX(0)
    __syncthreads();
    {
        LOADX(1)
        COMPUTE(0, 0)
        WRITEX(1)
        __syncthreads();
        LOADX(2)
        COMPUTE(1, 1)
        WRITEX(0)
        __syncthreads();
        LOADX(3)
        COMPUTE(2, 0)
        WRITEX(1)
        __syncthreads();
        COMPUTE(3, 1)
    }
    __syncthreads();   // all LDS reads done; reuse xs[0] for epilogue staging

    short* st_k = &xs[0][0];        // [32 t][72] pitch
    short* st_q = &xs[0][2304];     // [32 t][72]
    short* st_v = &xs[0][4608];     // [64 d][40] pitch (transposed)
#pragma unroll
    for (int j = 0; j < 6; ++j) {
        const int q = half * 6 + j, p = q >> 2, d16 = q & 3;
#pragma unroll
        for (int r = 0; r < 4; ++r) {
            const int mrow = m16 * 16 + g * 4 + r;
            const short v = f2bf(acc[j][r]);
            if (p == 0)      st_k[mrow * 72 + d16 * 16 + c] = v;
            else if (p == 1) st_q[mrow * 72 + d16 * 16 + c] = v;
            else             st_v[(d16 * 16 + c) * 40 + mrow] = v;
        }
    }
    __syncthreads();

    const int bb = row0 >> 11, ti = (row0 & 2047) >> 5;
    const size_t tb = ((size_t)(bb * 64 + ti)) * 4;
    const int fq = tid >> 6;               // ks (K/Q) or q-subfrag (V)
    const int l5 = lane & 31, h = lane >> 5;

    short8 kv = *(short8*)&st_k[l5 * 72 + fq * 16 + h * 8];
    *(short8*)&kfrag[(tb + fq) * 512 + lane * 8] = kv;
    short8 qv = *(short8*)&st_q[l5 * 72 + fq * 16 + h * 8];
    *(short8*)&qfrag[(tb + fq) * 512 + lane * 8] = qv;
    const int dh = fq >> 1, ssub = fq & 1;
    short8 vv = *(short8*)&st_v[(dh * 32 + l5) * 40 + ssub * 16 + h * 8];
    *(short8*)&vfrag[(tb + fq) * 512 + lane * 8] = vv;
}

// ---------------- attention (split-s, zero-LDS, coalesced frag loads) -------
__global__ __launch_bounds__(256, 4) void attn_kernel(
    const short* __restrict__ kfrag, const short* __restrict__ qfrag,
    const short* __restrict__ vfrag,
    u32* __restrict__ pO, float* __restrict__ pML)
{
    const int tid = threadIdx.x, wid = tid >> 6, lane = tid & 63;
    const int l5 = lane & 31, h = lane >> 5;
    const int b = blockIdx.y;

    int e = blockIdx.x, ck = 0;
    while (e >= 16 - ck) { e -= 16 - ck; ++ck; }
    const int i = 4 * (ck + e) + wid;       // t-tile (32 rows)
    const int st0 = 4 * ck;
    const int stEnd = min(st0 + 4, i + 1);

    const short* __restrict__ kb = kfrag + ((size_t)(b * 64 + i)) * 2048;
    const short* __restrict__ qb = qfrag + ((size_t)b * 64) * 2048;
    const short* __restrict__ vb = vfrag + ((size_t)b * 64) * 2048;

    short8 kf[4];
#pragma unroll
    for (int ks = 0; ks < 4; ++ks)
        kf[ks] = *(const short8*)&kb[ks * 512 + lane * 8];

    float m = -1e30f, l = 0.f;
    f32x16 o0 = {}, o1 = {};                 // O^T: rows=d (regs), col=t (lane)

    for (int st = st0; st < stEnd; ++st) {
        // ---- scores C[s][t] ----
        f32x16 Cs = {};
#pragma unroll
        for (int ks = 0; ks < 4; ++ks) {
            short8 qf = *(const short8*)&qb[((size_t)st * 4 + ks) * 512 + lane * 8];
            Cs = mfma32(qf, kf[ks], Cs);
        }
        if (st == i) {                       // diagonal tile: mask s > t
#pragma unroll
            for (int r = 0; r < 16; ++r) {
                const int srow = (r & 3) + 8 * (r >> 2) + 4 * h;
                if (srow > l5) Cs[r] = -1e30f;
            }
        }
        // ---- lane-scalar online softmax (t = l5) ----
        float mx = Cs[0];
#pragma unroll
        for (int r = 1; r < 16; ++r) mx = fmaxf(mx, Cs[r]);
        mx = fmaxf(mx, __shfl_xor(mx, 32));
        const float mnew = fmaxf(m, mx);
        const float alpha = exp2f(m - mnew);
        m = mnew;
        float pv[16]; float rs = 0.f;
#pragma unroll
        for (int r = 0; r < 16; ++r) { pv[r] = exp2f(Cs[r] - m); rs += pv[r]; }
        rs += __shfl_xor(rs, 32);
        l = l * alpha + rs;
#pragma unroll
        for (int r = 0; r < 16; ++r) { o0[r] *= alpha; o1[r] *= alpha; }

        // ---- pack P; build P^T B-frags via v_permlane32_swap (VALU) ----
        u32 pk[8];
#pragma unroll
        for (int q = 0; q < 8; ++q) pk[q] = packbf(pv[2 * q], pv[2 * q + 1]);
        u32 w0 = pk[0], w2 = pk[2];
        asm volatile("v_permlane32_swap_b32 %0, %1" : "+v"(w0), "+v"(w2));
        u32 w1 = pk[1], w3 = pk[3];
        asm volatile("v_permlane32_swap_b32 %0, %1" : "+v"(w1), "+v"(w3));
        u32 w4 = pk[4], w6 = pk[6];
        asm volatile("v_permlane32_swap_b32 %0, %1" : "+v"(w4), "+v"(w6));
        u32 w5 = pk[5], w7 = pk[7];
        asm volatile("v_permlane32_swap_b32 %0, %1" : "+v"(w5), "+v"(w7));
        short8 pf0, pf1;
        {
            u32 t0_ = w0, t1_ = w1, t2_ = w2, t3_ = w3;
            pf0[0] = (short)(t0_ & 0xffff); pf0[1] = (short)(t0_ >> 16);
            pf0[2] = (short)(t1_ & 0xffff); pf0[3] = (short)(t1_ >> 16);
            pf0[4] = (short)(t2_ & 0xffff); pf0[5] = (short)(t2_ >> 16);
            pf0[6] = (short)(t3_ & 0xffff); pf0[7] = (short)(t3_ >> 16);
            u32 t4_ = w4, t5_ = w5, t6_ = w6, t7_ = w7;
            pf1[0] = (short)(t4_ & 0xffff); pf1[1] = (short)(t4_ >> 16);
            pf1[2] = (short)(t5_ & 0xffff); pf1[3] = (short)(t5_ >> 16);
            pf1[4] = (short)(t6_ & 0xffff); pf1[5] = (short)(t6_ >> 16);
            pf1[6] = (short)(t7_ & 0xffff); pf1[7] = (short)(t7_ >> 16);
        }

        // ---- O^T += V^T * P^T (coalesced V-frag loads) ----
        const short* vt_ = &vb[((size_t)st * 4) * 512 + lane * 8];
        short8 v0 = *(const short8*)&vt_[0];
        short8 v1 = *(const short8*)&vt_[512];
        short8 v2 = *(const short8*)&vt_[1024];
        short8 v3 = *(const short8*)&vt_[1536];
        o0 = mfma32(v0, pf0, o0);
        o0 = mfma32(v1, pf1, o0);
        o1 = mfma32(v2, pf0, o1);
        o1 = mfma32(v3, pf1, o1);
    }

    // ---- partial store ----
    const int grp = i >> 2;
    const int slot = b * SLOTS + 2 * grp * (grp + 1) + (i & 3) * (grp + 1) + ck;
    u32* po = pO + (size_t)slot * 1024;
#pragma unroll
    for (int q = 0; q < 8; ++q) {
        const int dp = (q & 1) + 4 * (q >> 1) + 2 * h;
        po[dp * 32 + l5]        = packbf(o0[2 * q], o0[2 * q + 1]);
        po[(16 + dp) * 32 + l5] = packbf(o1[2 * q], o1[2 * q + 1]);
    }
    if (h == 0) {
        pML[(size_t)slot * 64 + l5]      = m;
        pML[(size_t)slot * 64 + 32 + l5] = l;
    }
}

// ---------------- combine partials ----------------
__global__ __launch_bounds__(256) void combine_kernel(
    const u32* __restrict__ pO, const float* __restrict__ pML,
    float* __restrict__ out)
{
    const int i = blockIdx.x, b = blockIdx.y;
    const int grp = i >> 2, nc = grp + 1;
    const int base = b * SLOTS + 2 * grp * (grp + 1) + (i & 3) * nc;
    const int tid = threadIdx.x;
    const int t = tid >> 3, ds8 = tid & 7;       // d = ds8*8 + 0..7

    float M = -1e30f;
    for (int c = 0; c < nc; ++c)
        M = fmaxf(M, pML[(size_t)(base + c) * 64 + t]);
    float L = 0.f;
    float acc[8] = {};
    for (int c = 0; c < nc; ++c) {
        const float mm = pML[(size_t)(base + c) * 64 + t];
        const float w = exp2f(mm - M);
        L += w * pML[(size_t)(base + c) * 64 + 32 + t];
        const u32* po = pO + (size_t)(base + c) * 1024;
#pragma unroll
        for (int u = 0; u < 4; ++u) {
            const u32 v = po[(ds8 * 4 + u) * 32 + t];
            acc[2 * u]     += w * bf2f((unsigned short)(v & 0xffff));
            acc[2 * u + 1] += w * bf2f((unsigned short)(v >> 16));
        }
    }
    const float inv = 1.f / L;
    f32x4 r0 = { acc[0] * inv, acc[1] * inv, acc[2] * inv, acc[3] * inv };
    f32x4 r1 = { acc[4] * inv, acc[5] * inv, acc[6] * inv, acc[7] * inv };
    float* op = out + ((size_t)b * T + i * 32 + t) * HD + ds8 * 8;
    *(f32x4*)op = r0;
    *(f32x4*)(op + 4) = r1;
}

extern "C" void kernel_launch(void* const* d_in, const int* in_sizes, int n_in,
                              void* d_out, int out_size, void* d_ws, size_t ws_size,
                              hipStream_t stream) {
    const float* x  = (const float*)d_in[0];
    const float* Wk = (const float*)d_in[1];
    const float* Wq = (const float*)d_in[2];
    const float* Wv = (const float*)d_in[3];
    float* out = (float*)d_out;

    short* kfrag = (short*)d_ws;                        // [512 tiles][4][64][8]
    short* qfrag = kfrag + (size_t)BATCH * T * HD;
    short* vfrag = qfrag + (size_t)BATCH * T * HD;
    short* wfrag = vfrag + (size_t)BATCH * T * HD;      // [3][4][32][64][8]
    u32*   pO    = (u32*)(wfrag + 3 * 65536);           // [4352][1024]
    float* pML   = (float*)(pO + (size_t)BATCH * SLOTS * 1024);  // [4352][64]

    wcvt_kernel<<<96, 256, 0, stream>>>(Wk, Wq, Wv, wfrag);
    proj_kernel<<<512, 256, 0, stream>>>(x, wfrag, kfrag, qfrag, vfrag);
    attn_kernel<<<dim3(136, BATCH), 256, 0, stream>>>(kfrag, qfrag, vfrag, pO, pML);
    combine_kernel<<<dim3(64, BATCH), 256, 0, stream>>>(pO, pML, out);
}

// Round 6
// 60.116 us; speedup vs baseline: 1.8988x; 1.6155x over previous
//
#include <hip/hip_runtime.h>
#include <hip/hip_bf16.h>

// B=8, T=2048, C=1024, H=64.  ref: wei=(k q^T)/32 causal, softmax over s, @v.
// R6: proj rebuilt: 1KB-contiguous per-instruction x loads (64 lanes x 16B),
// bf16 LDS staging with row-XOR swizzle (conflict-free b128 frag reads),
// 512-thread blocks (16 waves/CU). attn/wcvt unchanged from R5 (passing).

typedef __attribute__((ext_vector_type(8))) short short8;   // 8 bf16
typedef __attribute__((ext_vector_type(4))) float f32x4;
typedef __attribute__((ext_vector_type(16))) float f32x16;
typedef __attribute__((ext_vector_type(2))) unsigned int u32x2;
typedef unsigned int u32;

#define BATCH 8
#define T 2048
#define CDIM 1024
#define HD 64
#define SLOTS 544                 // split slots per batch
#define QK_SCALE 0.04508422f      // log2(e)/32  (exp2-domain softmax)

static __device__ __forceinline__ short f2bf(float f) {
    return __builtin_bit_cast(short, __float2bfloat16(f));   // RNE
}
static __device__ __forceinline__ float bf2f(unsigned short s) {
    u32 u = ((u32)s) << 16;
    return __builtin_bit_cast(float, u);
}
static __device__ __forceinline__ u32 packbf(float lo, float hi) {
    return (u32)(unsigned short)f2bf(lo) | ((u32)(unsigned short)f2bf(hi) << 16);
}
static __device__ __forceinline__ f32x4 mfma16(short8 a, short8 b, f32x4 c) {
    return __builtin_amdgcn_mfma_f32_16x16x32_bf16(a, b, c, 0, 0, 0);
}
static __device__ __forceinline__ f32x16 mfma32(short8 a, short8 b, f32x16 c) {
    return __builtin_amdgcn_mfma_f32_32x32x16_bf16(a, b, c, 0, 0, 0);
}

// ---------------- W -> frag-major bf16 (unchanged from R5) ----------------
__global__ __launch_bounds__(256) void wcvt_kernel(
    const float* __restrict__ Wk, const float* __restrict__ Wq,
    const float* __restrict__ Wv, short* __restrict__ wfrag)
{
    const int t = blockIdx.x * 256 + threadIdx.x;   // 0..24575
    const int lane = t & 63, kk = (t >> 6) & 31, d16 = (t >> 11) & 3, p = t >> 13;
    const float* __restrict__ W = (p == 0) ? Wk : (p == 1 ? Wq : Wv);
    const float sc = (p == 0) ? QK_SCALE : 1.0f;
    const float* src = W + (size_t)(d16 * 16 + (lane & 15)) * CDIM
                         + kk * 32 + ((lane >> 4) & 3) * 8;
    f32x4 a = *(const f32x4*)src;
    f32x4 b = *(const f32x4*)(src + 4);
    short8 o;
#pragma unroll
    for (int e = 0; e < 4; ++e) { o[e] = f2bf(a[e] * sc); o[e + 4] = f2bf(b[e] * sc); }
    *(short8*)(wfrag + (size_t)t * 8) = o;
}

// ---------------- projection ----------------
// 512 blocks x 512 thr (8 waves). Block = 32 rows x 192 cols (3 projs) x K=1024.
// Chunks of 256 k-floats, double-buffered bf16 LDS (16KB each).
// wave wid: m16 = wid&1 (16-row half), cg = wid>>1 (3 of 12 col-16-tiles).

#define PLOAD(KC) \
    _Pragma("unroll") for (int u = 0; u < 4; ++u) \
        xr[u] = *(const f32x4*)(x + (size_t)(row0 + u * 8 + wid) * CDIM + (KC) * 256 + lane * 4);

#define PWRITE(BUF) \
    _Pragma("unroll") for (int u = 0; u < 4; ++u) { \
        u32x2 pk2 = { packbf(xr[u][0], xr[u][1]), packbf(xr[u][2], xr[u][3]) }; \
        *(u32x2*)&xs[BUF][(u * 8 + wid) * 512 + ((lane * 8) ^ ((wid & 7) << 4))] = pk2; }

#define PCOMPUTE(KC, BUF) \
    _Pragma("unroll") for (int kk = 0; kk < 8; ++kk) { \
        short8 af = *(short8*)&xs[BUF][(m16 * 16 + c) * 512 + ((kk * 64 + g * 16) ^ ((c & 7) << 4))]; \
        _Pragma("unroll") for (int j = 0; j < 3; ++j) { \
            short8 bf = *(const short8*)&wfrag[(size_t)((cg * 3 + j) * 32 + (KC) * 8 + kk) * 512 + lane * 8]; \
            acc[j] = mfma16(af, bf, acc[j]); } }

__global__ __launch_bounds__(512, 4) void proj_kernel(
    const float* __restrict__ x, const short* __restrict__ wfrag,
    short* __restrict__ kfrag, short* __restrict__ qfrag, short* __restrict__ vfrag)
{
    __shared__ __align__(16) char xs[2][16384];

    const int tid = threadIdx.x, wid = tid >> 6, lane = tid & 63;
    const int c = lane & 15, g = lane >> 4;
    const int l5 = lane & 31, h = lane >> 5;
    const int row0 = blockIdx.x * 32;
    const int m16 = wid & 1, cg = wid >> 1;

    f32x4 xr[4];
    f32x4 acc[3] = {};

    PLOAD(0)
    PWRITE(0)
    __syncthreads();

    PLOAD(1)
    PCOMPUTE(0, 0)
    PWRITE(1)
    __syncthreads();

    PLOAD(2)
    PCOMPUTE(1, 1)
    PWRITE(0)
    __syncthreads();

    PLOAD(3)
    PCOMPUTE(2, 0)
    PWRITE(1)
    __syncthreads();

    PCOMPUTE(3, 1)
    __syncthreads();   // staging buffers free now

    // ---- epilogue: stage K/Q row-major, V transposed; then frag-major emit
    short* st_k = (short*)&xs[0][0];        // [32 t][72]
    short* st_q = (short*)&xs[0][9216];     // [32 t][72]
    short* st_v = (short*)&xs[1][0];        // [64 d][40]
#pragma unroll
    for (int j = 0; j < 3; ++j) {
        const int q = cg * 3 + j, p = q >> 2, d16 = q & 3;
#pragma unroll
        for (int r = 0; r < 4; ++r) {
            const int mrow = m16 * 16 + g * 4 + r;
            const short v = f2bf(acc[j][r]);
            if (p == 0)      st_k[mrow * 72 + d16 * 16 + c] = v;
            else if (p == 1) st_q[mrow * 72 + d16 * 16 + c] = v;
            else             st_v[(d16 * 16 + c) * 40 + mrow] = v;
        }
    }
    __syncthreads();

    const int bb = row0 >> 11, ti = (row0 & 2047) >> 5;
    const size_t tb = ((size_t)(bb * 64 + ti)) * 4;
    const int fq = wid & 3;
    if (wid < 4) {
        short8 kv = *(short8*)&st_k[l5 * 72 + fq * 16 + h * 8];
        *(short8*)&kfrag[(tb + fq) * 512 + lane * 8] = kv;
        const int dh = fq >> 1, ssub = fq & 1;
        short8 vv = *(short8*)&st_v[(dh * 32 + l5) * 40 + ssub * 16 + h * 8];
        *(short8*)&vfrag[(tb + fq) * 512 + lane * 8] = vv;
    } else {
        short8 qv = *(short8*)&st_q[l5 * 72 + fq * 16 + h * 8];
        *(short8*)&qfrag[(tb + fq) * 512 + lane * 8] = qv;
    }
}

// ---------------- attention (unchanged from R5) ----------------
__global__ __launch_bounds__(256, 4) void attn_kernel(
    const short* __restrict__ kfrag, const short* __restrict__ qfrag,
    const short* __restrict__ vfrag,
    u32* __restrict__ pO, float* __restrict__ pML)
{
    const int tid = threadIdx.x, wid = tid >> 6, lane = tid & 63;
    const int l5 = lane & 31, h = lane >> 5;
    const int b = blockIdx.y;

    int e = blockIdx.x, ck = 0;
    while (e >= 16 - ck) { e -= 16 - ck; ++ck; }
    const int i = 4 * (ck + e) + wid;       // t-tile (32 rows)
    const int st0 = 4 * ck;
    const int stEnd = min(st0 + 4, i + 1);

    const short* __restrict__ kb = kfrag + ((size_t)(b * 64 + i)) * 2048;
    const short* __restrict__ qb = qfrag + ((size_t)b * 64) * 2048;
    const short* __restrict__ vb = vfrag + ((size_t)b * 64) * 2048;

    short8 kf[4];
#pragma unroll
    for (int ks = 0; ks < 4; ++ks)
        kf[ks] = *(const short8*)&kb[ks * 512 + lane * 8];

    float m = -1e30f, l = 0.f;
    f32x16 o0 = {}, o1 = {};                 // O^T: rows=d (regs), col=t (lane)

    for (int st = st0; st < stEnd; ++st) {
        f32x16 Cs = {};
#pragma unroll
        for (int ks = 0; ks < 4; ++ks) {
            short8 qf = *(const short8*)&qb[((size_t)st * 4 + ks) * 512 + lane * 8];
            Cs = mfma32(qf, kf[ks], Cs);
        }
        if (st == i) {                       // diagonal tile: mask s > t
#pragma unroll
            for (int r = 0; r < 16; ++r) {
                const int srow = (r & 3) + 8 * (r >> 2) + 4 * h;
                if (srow > l5) Cs[r] = -1e30f;
            }
        }
        float mx = Cs[0];
#pragma unroll
        for (int r = 1; r < 16; ++r) mx = fmaxf(mx, Cs[r]);
        mx = fmaxf(mx, __shfl_xor(mx, 32));
        const float mnew = fmaxf(m, mx);
        const float alpha = exp2f(m - mnew);
        m = mnew;
        float pv[16]; float rs = 0.f;
#pragma unroll
        for (int r = 0; r < 16; ++r) { pv[r] = exp2f(Cs[r] - m); rs += pv[r]; }
        rs += __shfl_xor(rs, 32);
        l = l * alpha + rs;
#pragma unroll
        for (int r = 0; r < 16; ++r) { o0[r] *= alpha; o1[r] *= alpha; }

        u32 pk[8];
#pragma unroll
        for (int q = 0; q < 8; ++q) pk[q] = packbf(pv[2 * q], pv[2 * q + 1]);
        u32 w0 = pk[0], w2 = pk[2];
        asm volatile("v_permlane32_swap_b32 %0, %1" : "+v"(w0), "+v"(w2));
        u32 w1 = pk[1], w3 = pk[3];
        asm volatile("v_permlane32_swap_b32 %0, %1" : "+v"(w1), "+v"(w3));
        u32 w4 = pk[4], w6 = pk[6];
        asm volatile("v_permlane32_swap_b32 %0, %1" : "+v"(w4), "+v"(w6));
        u32 w5 = pk[5], w7 = pk[7];
        asm volatile("v_permlane32_swap_b32 %0, %1" : "+v"(w5), "+v"(w7));
        short8 pf0, pf1;
        pf0[0] = (short)(w0 & 0xffff); pf0[1] = (short)(w0 >> 16);
        pf0[2] = (short)(w1 & 0xffff); pf0[3] = (short)(w1 >> 16);
        pf0[4] = (short)(w2 & 0xffff); pf0[5] = (short)(w2 >> 16);
        pf0[6] = (short)(w3 & 0xffff); pf0[7] = (short)(w3 >> 16);
        pf1[0] = (short)(w4 & 0xffff); pf1[1] = (short)(w4 >> 16);
        pf1[2] = (short)(w5 & 0xffff); pf1[3] = (short)(w5 >> 16);
        pf1[4] = (short)(w6 & 0xffff); pf1[5] = (short)(w6 >> 16);
        pf1[6] = (short)(w7 & 0xffff); pf1[7] = (short)(w7 >> 16);

        const short* vt_ = &vb[((size_t)st * 4) * 512 + lane * 8];
        short8 v0 = *(const short8*)&vt_[0];
        short8 v1 = *(const short8*)&vt_[512];
        short8 v2 = *(const short8*)&vt_[1024];
        short8 v3 = *(const short8*)&vt_[1536];
        o0 = mfma32(v0, pf0, o0);
        o0 = mfma32(v1, pf1, o0);
        o1 = mfma32(v2, pf0, o1);
        o1 = mfma32(v3, pf1, o1);
    }

    const int grp = i >> 2;
    const int slot = b * SLOTS + 2 * grp * (grp + 1) + (i & 3) * (grp + 1) + ck;
    u32* po = pO + (size_t)slot * 1024;
#pragma unroll
    for (int q = 0; q < 8; ++q) {
        const int dp = (q & 1) + 4 * (q >> 1) + 2 * h;
        po[dp * 32 + l5]        = packbf(o0[2 * q], o0[2 * q + 1]);
        po[(16 + dp) * 32 + l5] = packbf(o1[2 * q], o1[2 * q + 1]);
    }
    if (h == 0) {
        pML[(size_t)slot * 64 + l5]      = m;
        pML[(size_t)slot * 64 + 32 + l5] = l;
    }
}

// ---------------- combine partials (lane-major t for coalesced gathers) -----
__global__ __launch_bounds__(256) void combine_kernel(
    const u32* __restrict__ pO, const float* __restrict__ pML,
    float* __restrict__ out)
{
    const int i = blockIdx.x, b = blockIdx.y;
    const int grp = i >> 2, nc = grp + 1;
    const int base = b * SLOTS + 2 * grp * (grp + 1) + (i & 3) * nc;
    const int tid = threadIdx.x;
    const int t = tid & 31, ds8 = tid >> 5;      // d = ds8*8 + 0..7

    float M = -1e30f;
    for (int c = 0; c < nc; ++c)
        M = fmaxf(M, pML[(size_t)(base + c) * 64 + t]);
    float L = 0.f;
    float acc[8] = {};
    for (int c = 0; c < nc; ++c) {
        const float mm = pML[(size_t)(base + c) * 64 + t];
        const float w = exp2f(mm - M);
        L += w * pML[(size_t)(base + c) * 64 + 32 + t];
        const u32* po = pO + (size_t)(base + c) * 1024;
#pragma unroll
        for (int u = 0; u < 4; ++u) {
            const u32 v = po[(ds8 * 4 + u) * 32 + t];
            acc[2 * u]     += w * bf2f((unsigned short)(v & 0xffff));
            acc[2 * u + 1] += w * bf2f((unsigned short)(v >> 16));
        }
    }
    const float inv = 1.f / L;
    f32x4 r0 = { acc[0] * inv, acc[1] * inv, acc[2] * inv, acc[3] * inv };
    f32x4 r1 = { acc[4] * inv, acc[5] * inv, acc[6] * inv, acc[7] * inv };
    float* op = out + ((size_t)b * T + i * 32 + t) * HD + ds8 * 8;
    *(f32x4*)op = r0;
    *(f32x4*)(op + 4) = r1;
}

extern "C" void kernel_launch(void* const* d_in, const int* in_sizes, int n_in,
                              void* d_out, int out_size, void* d_ws, size_t ws_size,
                              hipStream_t stream) {
    const float* x  = (const float*)d_in[0];
    const float* Wk = (const float*)d_in[1];
    const float* Wq = (const float*)d_in[2];
    const float* Wv = (const float*)d_in[3];
    float* out = (float*)d_out;

    short* kfrag = (short*)d_ws;                        // [512 tiles][4][64][8]
    short* qfrag = kfrag + (size_t)BATCH * T * HD;
    short* vfrag = qfrag + (size_t)BATCH * T * HD;
    short* wfrag = vfrag + (size_t)BATCH * T * HD;      // [12][32][64][8]
    u32*   pO    = (u32*)(wfrag + 3 * 65536);           // [4352][1024]
    float* pML   = (float*)(pO + (size_t)BATCH * SLOTS * 1024);  // [4352][64]

    wcvt_kernel<<<96, 256, 0, stream>>>(Wk, Wq, Wv, wfrag);
    proj_kernel<<<512, 512, 0, stream>>>(x, wfrag, kfrag, qfrag, vfrag);
    attn_kernel<<<dim3(136, BATCH), 256, 0, stream>>>(kfrag, qfrag, vfrag, pO, pML);
    combine_kernel<<<dim3(64, BATCH), 256, 0, stream>>>(pO, pML, out);
}